// Round 18
// baseline (46.061 us; speedup 1.0000x reference)
//
#include <hip/hip_runtime.h>

typedef __attribute__((ext_vector_type(2))) _Float16 half2v;
typedef __attribute__((ext_vector_type(8))) _Float16 half8v;
typedef __attribute__((ext_vector_type(8))) unsigned short ushort8v;
typedef __attribute__((ext_vector_type(4))) float f32x4;
typedef __attribute__((ext_vector_type(2))) unsigned u32x2;

#define NBLK 1024
#define WP_ELEMS (9 * 4 * 16 * 8)
#define RP_OFF 16384
#define F16_OFF (16384 + 262144)
#define MS_OFF (F16_OFF + 2097152)

// Setup: Wz f16 pack + row_ptr (lower_bound) + f16 feat replica.
// NT policy: ONLY pure-input streams are nontemporal (efeat/src/feat reads).
// Device-written RAW chains (ms, out) use normal ops — nt on them caused the
// R17 coherence failure (stale reads around L2).
__global__ __launch_bounds__(256) void setup_kernel(
    const float* __restrict__ We, const float* __restrict__ be,
    const float* __restrict__ feat, const int* __restrict__ dst,
    unsigned short* __restrict__ wp, int* __restrict__ rp,
    unsigned short* __restrict__ f16, int E, int N) {
  int idx = blockIdx.x * 256 + threadIdx.x;
  if (idx < WP_ELEMS) {
    int j = idx & 7, n = (idx >> 3) & 15, gg = (idx >> 7) & 3, t = idx >> 9;
    float v = 0.f;
    if (t < 8) {
      int c = (gg >> 1) * 8 + t;
      int i = (gg & 1) * 8 + j;
      v = We[c * 256 + i * 16 + n];
    } else if (gg < 2) {
      v = be[(gg * 8 + j) * 16 + n];
    }
    _Float16 hv = (_Float16)v;
    wp[idx] = __builtin_bit_cast(unsigned short, hv);
  }
  if (idx <= N) {
    int lo = 0, hi = E;
    while (lo < hi) {
      int mid = (lo + hi) >> 1;
      if (dst[mid] < idx) lo = mid + 1; else hi = mid;
    }
    rp[idx] = lo;
  }
  if (idx * 4 < N * 16) {  // f16 replica (feat is input-only -> nt load safe)
    f32x4 v = __builtin_nontemporal_load(
        reinterpret_cast<const f32x4*>(feat + idx * 4));
    half2v a{(_Float16)v[0], (_Float16)v[1]};
    half2v b{(_Float16)v[2], (_Float16)v[3]};
    u32x2 w;
    w[0] = __builtin_bit_cast(unsigned, a);
    w[1] = __builtin_bit_cast(unsigned, b);
    *reinterpret_cast<u32x2*>(f16 + idx * 4) = w;   // normal store (device-written)
  }
}

struct Bank { f32x4 ea, eb; ushort8v h; };

// issue loads for super-tile ni: efeat/src NONTEMPORAL (input streams, keep out
// of L2 so the f16 gather table stays resident); H gather NORMAL (wants L2).
__device__ __forceinline__ void issue_grp(
    Bank& bk, int ni, int n4, int& ss, int E,
    const f32x4* __restrict__ ef4, const ushort8v* __restrict__ f16v,
    const int* __restrict__ src, int eE, int qE, int eH, int qH) {
  int b0 = ni * 32;
  bk.ea = __builtin_nontemporal_load(&ef4[(unsigned)min(b0 + eE, E - 1) * 4 + qE]);
  bk.eb = __builtin_nontemporal_load(&ef4[(unsigned)min(b0 + 16 + eE, E - 1) * 4 + qE]);
  bk.h  = f16v[(unsigned)ss * 2 + qH];
  ss = __builtin_nontemporal_load(&src[min(n4 * 32 + eH, E - 1)]);
}

// stage bank -> LDS buf. EF region: [32 edges][48B stride]; HF at +1536.
__device__ __forceinline__ void stage_grp(
    char* __restrict__ buf, const Bank& bk, int ni, int E,
    int eE, int qE, int eH, int qH) {
  half2v x0{(_Float16)bk.ea[0], (_Float16)bk.ea[1]};
  half2v x1{(_Float16)bk.ea[2], (_Float16)bk.ea[3]};
  half2v y0{(_Float16)bk.eb[0], (_Float16)bk.eb[1]};
  half2v y1{(_Float16)bk.eb[2], (_Float16)bk.eb[3]};
  u32x2 w0, w1;
  w0[0] = __builtin_bit_cast(unsigned, x0); w0[1] = __builtin_bit_cast(unsigned, x1);
  w1[0] = __builtin_bit_cast(unsigned, y0); w1[1] = __builtin_bit_cast(unsigned, y1);
  if ((ni * 32 + eE) >= E)      { w0[0] = 0; w0[1] = 0; }
  if ((ni * 32 + 16 + eE) >= E) { w1[0] = 0; w1[1] = 0; }
  *reinterpret_cast<u32x2*>(buf + eE * 48 + qE * 8) = w0;
  *reinterpret_cast<u32x2*>(buf + (16 + eE) * 48 + qE * 8) = w1;
  ushort8v hv = bk.h;
  if ((ni * 32 + eH) >= E) hv = (ushort8v){0, 0, 0, 0, 0, 0, 0, 0};
  *reinterpret_cast<ushort8v*>(buf + 1536 + eH * 48 + qH * 16) = hv;
}

// compute both MFMA tiles of super-tile ni from LDS; NORMAL D-frag store.
__device__ __forceinline__ void compute_st(
    unsigned short* __restrict__ ms, const char* __restrict__ buf,
    int ni, int E, int g, int m, int lane, const half8v* Bf) {
  int p = g >> 1, hh = g & 1;
#pragma unroll
  for (int tt = 0; tt < 2; ++tt) {
    if ((ni * 32 + tt * 16) >= E) break;  // wave-uniform
    half8v efr = *reinterpret_cast<const half8v*>(buf + (tt * 16 + m) * 48 + p * 16);
    half8v hfr = *reinterpret_cast<const half8v*>(buf + 1536 + (tt * 16 + m) * 48 + hh * 16);
    half2v ef2[4], h2[4];
#pragma unroll
    for (int j = 0; j < 4; ++j) {
      ef2[j] = half2v{efr[2 * j], efr[2 * j + 1]};
      h2[j]  = half2v{hfr[2 * j], hfr[2 * j + 1]};
    }
    f32x4 accA = {0.f, 0.f, 0.f, 0.f};
    f32x4 accB = {0.f, 0.f, 0.f, 0.f};
#pragma unroll
    for (int t = 0; t < 8; ++t) {
      _Float16 ev = ef2[t >> 1][t & 1];
      half2v evb = half2v{ev, ev};
      half2v a0 = evb * h2[0], a1 = evb * h2[1], a2 = evb * h2[2], a3 = evb * h2[3];
      half8v A;
      A[0] = a0[0]; A[1] = a0[1]; A[2] = a1[0]; A[3] = a1[1];
      A[4] = a2[0]; A[5] = a2[1]; A[6] = a3[0]; A[7] = a3[1];
      if (t & 1)
        accB = __builtin_amdgcn_mfma_f32_16x16x32_f16(A, Bf[t], accB, 0, 0, 0);
      else
        accA = __builtin_amdgcn_mfma_f32_16x16x32_f16(A, Bf[t], accA, 0, 0, 0);
    }
    {  // be passthrough K-tile
      half2v z{(_Float16)0.f, (_Float16)0.f};
      half2v b0 = (g < 2) ? h2[0] : z, b1 = (g < 2) ? h2[1] : z;
      half2v b2 = (g < 2) ? h2[2] : z, b3 = (g < 2) ? h2[3] : z;
      half8v A;
      A[0] = b0[0]; A[1] = b0[1]; A[2] = b1[0]; A[3] = b1[1];
      A[4] = b2[0]; A[5] = b2[1]; A[6] = b3[0]; A[7] = b3[1];
      accB = __builtin_amdgcn_mfma_f32_16x16x32_f16(A, Bf[8], accB, 0, 0, 0);
    }
    half2v lo{(_Float16)(accA[0] + accB[0]), (_Float16)(accA[1] + accB[1])};
    half2v hi{(_Float16)(accA[2] + accB[2]), (_Float16)(accA[3] + accB[3])};
    u32x2 w;
    w[0] = __builtin_bit_cast(unsigned, lo);
    w[1] = __builtin_bit_cast(unsigned, hi);
    *reinterpret_cast<u32x2*>(ms + (size_t)(2 * ni + tt) * 256 + lane * 4) = w;
  }
}

// Phase A: 32-edge super-tiles, depth-2 pipeline, static banks P/Q, vmcnt(6).
__global__ __launch_bounds__(256) void edge_gemm_kernel(
    const float* __restrict__ efeat, const int* __restrict__ src,
    const unsigned short* __restrict__ wp, const unsigned short* __restrict__ f16,
    unsigned short* __restrict__ ms, int E) {
  __shared__ __align__(16) char lds[4][2][3072];
  int wid = threadIdx.x >> 6, lane = threadIdx.x & 63;
  int g = lane >> 4, m = lane & 15;
  int eE = lane >> 2, qE = lane & 3, eH = lane >> 1, qH = lane & 1;

  int nst = (E + 31) >> 5;
  int CW = gridDim.x * 4;
  int n = blockIdx.x * 4 + wid;
  if (n >= nst) return;

  half8v Bf[9];
#pragma unroll
  for (int t = 0; t < 9; ++t)
    Bf[t] = *reinterpret_cast<const half8v*>(wp + (unsigned)(t * 64 + lane) * 8);

  const f32x4* ef4 = reinterpret_cast<const f32x4*>(efeat);
  const ushort8v* f16v = reinterpret_cast<const ushort8v*>(f16);
  char* buf0 = &lds[wid][0][0];
  char* buf1 = &lds[wid][1][0];

  int n1 = n + CW, n2 = n1 + CW, n3 = n2 + CW;
  int CW2 = 2 * CW;
  Bank P, Q;
  int ssA, ssB;

  // ---- prologue ----
  {
    int ss0 = __builtin_nontemporal_load(&src[min(n * 32 + eH, E - 1)]);
    Q.ea = __builtin_nontemporal_load(&ef4[(unsigned)min(n * 32 + eE, E - 1) * 4 + qE]);
    Q.eb = __builtin_nontemporal_load(&ef4[(unsigned)min(n * 32 + 16 + eE, E - 1) * 4 + qE]);
    Q.h  = f16v[(unsigned)ss0 * 2 + qH];
    ssA  = __builtin_nontemporal_load(&src[min(n2 * 32 + eH, E - 1)]);
    int ss1 = __builtin_nontemporal_load(&src[min(n1 * 32 + eH, E - 1)]);
    stage_grp(buf0, Q, n, E, eE, qE, eH, qH);
    P.ea = __builtin_nontemporal_load(&ef4[(unsigned)min(n1 * 32 + eE, E - 1) * 4 + qE]);
    P.eb = __builtin_nontemporal_load(&ef4[(unsigned)min(n1 * 32 + 16 + eE, E - 1) * 4 + qE]);
    P.h  = f16v[(unsigned)ss1 * 2 + qH];
    ssB  = __builtin_nontemporal_load(&src[min(n3 * 32 + eH, E - 1)]);
  }

  while (true) {
    // ---- even half ----
    issue_grp(Q, n2, n2 + CW2, ssA, E, ef4, f16v, src, eE, qE, eH, qH);
    __builtin_amdgcn_sched_barrier(0);
    compute_st(ms, buf0, n, E, g, m, lane, Bf);
    __builtin_amdgcn_sched_barrier(0);
    if (n1 >= nst) return;
    asm volatile("s_waitcnt vmcnt(6)" ::: "memory");
    __builtin_amdgcn_sched_barrier(0);
    stage_grp(buf1, P, n1, E, eE, qE, eH, qH);

    // ---- odd half ----
    issue_grp(P, n3, n3 + CW2, ssB, E, ef4, f16v, src, eE, qE, eH, qH);
    __builtin_amdgcn_sched_barrier(0);
    compute_st(ms, buf1, n1, E, g, m, lane, Bf);
    __builtin_amdgcn_sched_barrier(0);
    if (n2 >= nst) return;
    asm volatile("s_waitcnt vmcnt(6)" ::: "memory");
    __builtin_amdgcn_sched_barrier(0);
    stage_grp(buf0, Q, n2, E, eE, qE, eH, qH);

    n += CW2; n1 += CW2; n2 += CW2; n3 += CW2;
  }
}

// fragment-layout index of m[e][c]: (e>>4)*256 + ((e>>2)&3)*64 + c*4 + (e&3)
__device__ __forceinline__ float ms_at(const unsigned short* ms, int e, int c) {
  unsigned short u = ms[((e >> 4) << 8) + (((e >> 2) & 3) << 6) + (c << 2) + (e & 3)];
  return (float)__builtin_bit_cast(_Float16, u);
}

// Phase B: one 16-lane group per node; NORMAL loads/stores (ms is device-written).
__global__ __launch_bounds__(256) void segsum_kernel(
    const float* __restrict__ feat, const float* __restrict__ bias,
    const unsigned short* __restrict__ ms, const int* __restrict__ rp,
    float* __restrict__ out, int N) {
  int n = blockIdx.x * 16 + (threadIdx.x >> 4);
  int c = threadIdx.x & 15;
  if (n >= N) return;
  int lo = rp[n], hi = rp[n + 1];
  float sum = 0.f;
  int e = lo;
  while (e < hi && (e & 3)) { sum += ms_at(ms, e, c); ++e; }
  while (e + 4 <= hi) {
    const uint2 v = *reinterpret_cast<const uint2*>(
        ms + ((e >> 4) << 8) + (((e >> 2) & 3) << 6) + (c << 2));
    half2v x = __builtin_bit_cast(half2v, v.x);
    half2v y = __builtin_bit_cast(half2v, v.y);
    sum += (float)x[0] + (float)x[1] + (float)y[0] + (float)y[1];
    e += 4;
  }
  while (e < hi) { sum += ms_at(ms, e, c); ++e; }
  out[n * 16 + c] = sum + feat[n * 16 + c] + bias[c];
}

extern "C" void kernel_launch(void* const* d_in, const int* in_sizes, int n_in,
                              void* d_out, int out_size, void* d_ws, size_t ws_size,
                              hipStream_t stream) {
  const float* feat  = (const float*)d_in[0];
  const float* efeat = (const float*)d_in[1];
  const float* We    = (const float*)d_in[2];
  const float* be    = (const float*)d_in[3];
  const float* bias  = (const float*)d_in[4];
  const int*   src   = (const int*)d_in[5];
  const int*   dst   = (const int*)d_in[6];
  float* out = (float*)d_out;

  int E = in_sizes[5];
  int N = out_size / 16;

  unsigned short* wp  = (unsigned short*)d_ws;
  int* rp             = (int*)((char*)d_ws + RP_OFF);
  unsigned short* f16 = (unsigned short*)((char*)d_ws + F16_OFF);
  unsigned short* ms  = (unsigned short*)((char*)d_ws + MS_OFF);

  int sitems = WP_ELEMS;
  if (N + 1 > sitems) sitems = N + 1;
  if (N * 4 > sitems) sitems = N * 4;
  setup_kernel<<<(sitems + 255) / 256, 256, 0, stream>>>(We, be, feat, dst,
                                                         wp, rp, f16, E, N);

  int nst = (E + 31) / 32;
  int blocksA = min(NBLK, (nst + 3) / 4);
  edge_gemm_kernel<<<blocksA, 256, 0, stream>>>(efeat, src, wp, f16, ms, E);

  int blocksB = (N + 15) / 16;
  segsum_kernel<<<blocksB, 256, 0, stream>>>(feat, bias, ms, rp, out, N);
}

// Round 19
// 41.019 us; speedup vs baseline: 1.1229x; 1.1229x over previous
//
#include <hip/hip_runtime.h>

typedef __attribute__((ext_vector_type(2))) _Float16 half2v;
typedef __attribute__((ext_vector_type(8))) _Float16 half8v;
typedef __attribute__((ext_vector_type(8))) unsigned short ushort8v;
typedef __attribute__((ext_vector_type(4))) float f32x4;

#define NBLK 1024
#define WP_ELEMS (9 * 4 * 16 * 8)
#define RP_OFF 16384
#define F16_OFF (16384 + 262144)
#define MS_OFF (F16_OFF + 2097152)

// Setup: Wz f16 pack + row_ptr (lower_bound) + f16 feat replica.
__global__ __launch_bounds__(256) void setup_kernel(
    const float* __restrict__ We, const float* __restrict__ be,
    const float* __restrict__ feat, const int* __restrict__ dst,
    unsigned short* __restrict__ wp, int* __restrict__ rp,
    unsigned short* __restrict__ f16, int E, int N) {
  int idx = blockIdx.x * 256 + threadIdx.x;
  if (idx < WP_ELEMS) {
    int j = idx & 7, n = (idx >> 3) & 15, gg = (idx >> 7) & 3, t = idx >> 9;
    float v = 0.f;
    if (t < 8) {
      int c = (gg >> 1) * 8 + t;
      int i = (gg & 1) * 8 + j;
      v = We[c * 256 + i * 16 + n];
    } else if (gg < 2) {
      v = be[(gg * 8 + j) * 16 + n];
    }
    _Float16 hv = (_Float16)v;
    wp[idx] = __builtin_bit_cast(unsigned short, hv);
  }
  if (idx <= N) {
    int lo = 0, hi = E;
    while (lo < hi) {
      int mid = (lo + hi) >> 1;
      if (dst[mid] < idx) lo = mid + 1; else hi = mid;
    }
    rp[idx] = lo;
  }
  if (idx * 4 < N * 16) {  // f16 replica, 4 elems/thread
    float4 v = *reinterpret_cast<const float4*>(feat + idx * 4);
    half2v a{(_Float16)v.x, (_Float16)v.y};
    half2v b{(_Float16)v.z, (_Float16)v.w};
    uint2 w;
    w.x = __builtin_bit_cast(unsigned, a);
    w.y = __builtin_bit_cast(unsigned, b);
    *reinterpret_cast<uint2*>(f16 + idx * 4) = w;
  }
}

struct Bank { float4 ea, eb; ushort8v h; };

// issue loads for super-tile ni (32 edges): 2 efeat instrs, 1 H instr (f16 rows,
// addressed by ss loaded 2 groups ago), 1 src instr carried for group ni+2CW2.
__device__ __forceinline__ void issue_grp(
    Bank& bk, int ni, int n4, int& ss, int E,
    const float4* __restrict__ ef4, const ushort8v* __restrict__ f16v,
    const int* __restrict__ src, int eE, int qE, int eH, int qH) {
  int b0 = ni * 32;
  bk.ea = ef4[(unsigned)min(b0 + eE, E - 1) * 4 + qE];
  bk.eb = ef4[(unsigned)min(b0 + 16 + eE, E - 1) * 4 + qE];
  bk.h  = f16v[(unsigned)ss * 2 + qH];
  ss = src[min(n4 * 32 + eH, E - 1)];
}

// stage bank -> LDS buf. EF region: [32 edges][48B stride], ch c at e*48+c*2.
// HF region at +1536, same stride. Invalid edges -> zeros (kills be-tile too).
__device__ __forceinline__ void stage_grp(
    char* __restrict__ buf, const Bank& bk, int ni, int E,
    int eE, int qE, int eH, int qH) {
  half2v x0{(_Float16)bk.ea.x, (_Float16)bk.ea.y};
  half2v x1{(_Float16)bk.ea.z, (_Float16)bk.ea.w};
  half2v y0{(_Float16)bk.eb.x, (_Float16)bk.eb.y};
  half2v y1{(_Float16)bk.eb.z, (_Float16)bk.eb.w};
  uint2 w0, w1;
  w0.x = __builtin_bit_cast(unsigned, x0); w0.y = __builtin_bit_cast(unsigned, x1);
  w1.x = __builtin_bit_cast(unsigned, y0); w1.y = __builtin_bit_cast(unsigned, y1);
  if ((ni * 32 + eE) >= E)      { w0.x = 0; w0.y = 0; }
  if ((ni * 32 + 16 + eE) >= E) { w1.x = 0; w1.y = 0; }
  *reinterpret_cast<uint2*>(buf + eE * 48 + qE * 8) = w0;
  *reinterpret_cast<uint2*>(buf + (16 + eE) * 48 + qE * 8) = w1;
  ushort8v hv = bk.h;
  if ((ni * 32 + eH) >= E) hv = (ushort8v){0, 0, 0, 0, 0, 0, 0, 0};
  *reinterpret_cast<ushort8v*>(buf + 1536 + eH * 48 + qH * 16) = hv;
}

// compute both MFMA tiles of super-tile ni from LDS; store D-frag f16 to ms.
__device__ __forceinline__ void compute_st(
    unsigned short* __restrict__ ms, const char* __restrict__ buf,
    int ni, int E, int g, int m, int lane, const half8v* Bf) {
  int p = g >> 1, hh = g & 1;
#pragma unroll
  for (int tt = 0; tt < 2; ++tt) {
    if ((ni * 32 + tt * 16) >= E) break;  // wave-uniform
    half8v efr = *reinterpret_cast<const half8v*>(buf + (tt * 16 + m) * 48 + p * 16);
    half8v hfr = *reinterpret_cast<const half8v*>(buf + 1536 + (tt * 16 + m) * 48 + hh * 16);
    half2v ef2[4], h2[4];
#pragma unroll
    for (int j = 0; j < 4; ++j) {
      ef2[j] = half2v{efr[2 * j], efr[2 * j + 1]};
      h2[j]  = half2v{hfr[2 * j], hfr[2 * j + 1]};
    }
    f32x4 accA = {0.f, 0.f, 0.f, 0.f};
    f32x4 accB = {0.f, 0.f, 0.f, 0.f};
#pragma unroll
    for (int t = 0; t < 8; ++t) {
      _Float16 ev = ef2[t >> 1][t & 1];
      half2v evb = half2v{ev, ev};
      half2v a0 = evb * h2[0], a1 = evb * h2[1], a2 = evb * h2[2], a3 = evb * h2[3];
      half8v A;
      A[0] = a0[0]; A[1] = a0[1]; A[2] = a1[0]; A[3] = a1[1];
      A[4] = a2[0]; A[5] = a2[1]; A[6] = a3[0]; A[7] = a3[1];
      if (t & 1)
        accB = __builtin_amdgcn_mfma_f32_16x16x32_f16(A, Bf[t], accB, 0, 0, 0);
      else
        accA = __builtin_amdgcn_mfma_f32_16x16x32_f16(A, Bf[t], accA, 0, 0, 0);
    }
    {  // be passthrough K-tile
      half2v z{(_Float16)0.f, (_Float16)0.f};
      half2v b0 = (g < 2) ? h2[0] : z, b1 = (g < 2) ? h2[1] : z;
      half2v b2 = (g < 2) ? h2[2] : z, b3 = (g < 2) ? h2[3] : z;
      half8v A;
      A[0] = b0[0]; A[1] = b0[1]; A[2] = b1[0]; A[3] = b1[1];
      A[4] = b2[0]; A[5] = b2[1]; A[6] = b3[0]; A[7] = b3[1];
      accB = __builtin_amdgcn_mfma_f32_16x16x32_f16(A, Bf[8], accB, 0, 0, 0);
    }
    half2v lo{(_Float16)(accA[0] + accB[0]), (_Float16)(accA[1] + accB[1])};
    half2v hi{(_Float16)(accA[2] + accB[2]), (_Float16)(accA[3] + accB[3])};
    uint2 w;
    w.x = __builtin_bit_cast(unsigned, lo);
    w.y = __builtin_bit_cast(unsigned, hi);
    *reinterpret_cast<uint2*>(ms + (size_t)(2 * ni + tt) * 256 + lane * 4) = w;
  }
}

// Phase A: 32-edge super-tiles, depth-2 pipeline, two static reg banks (P/Q),
// unroll x2 (no cross-bank copies -> no forced waits), counted vmcnt(6).
__global__ __launch_bounds__(256) void edge_gemm_kernel(
    const float* __restrict__ efeat, const int* __restrict__ src,
    const unsigned short* __restrict__ wp, const unsigned short* __restrict__ f16,
    unsigned short* __restrict__ ms, int E) {
  __shared__ __align__(16) char lds[4][2][3072];
  int wid = threadIdx.x >> 6, lane = threadIdx.x & 63;
  int g = lane >> 4, m = lane & 15;
  int eE = lane >> 2, qE = lane & 3, eH = lane >> 1, qH = lane & 1;

  int nst = (E + 31) >> 5;
  int CW = gridDim.x * 4;
  int n = blockIdx.x * 4 + wid;
  if (n >= nst) return;

  half8v Bf[9];
#pragma unroll
  for (int t = 0; t < 9; ++t)
    Bf[t] = *reinterpret_cast<const half8v*>(wp + (unsigned)(t * 64 + lane) * 8);

  const float4* ef4 = reinterpret_cast<const float4*>(efeat);
  const ushort8v* f16v = reinterpret_cast<const ushort8v*>(f16);
  char* buf0 = &lds[wid][0][0];
  char* buf1 = &lds[wid][1][0];

  int n1 = n + CW, n2 = n1 + CW, n3 = n2 + CW;
  int CW2 = 2 * CW;
  Bank P, Q;
  int ssA, ssB;

  // ---- prologue: group(n) -> Q -> buf0; group(n1) -> P (left in flight) ----
  {
    int ss0 = src[min(n * 32 + eH, E - 1)];
    Q.ea = ef4[(unsigned)min(n * 32 + eE, E - 1) * 4 + qE];
    Q.eb = ef4[(unsigned)min(n * 32 + 16 + eE, E - 1) * 4 + qE];
    Q.h  = f16v[(unsigned)ss0 * 2 + qH];
    ssA  = src[min(n2 * 32 + eH, E - 1)];
    int ss1 = src[min(n1 * 32 + eH, E - 1)];
    stage_grp(buf0, Q, n, E, eE, qE, eH, qH);
    P.ea = ef4[(unsigned)min(n1 * 32 + eE, E - 1) * 4 + qE];
    P.eb = ef4[(unsigned)min(n1 * 32 + 16 + eE, E - 1) * 4 + qE];
    P.h  = f16v[(unsigned)ss1 * 2 + qH];
    ssB  = src[min(n3 * 32 + eH, E - 1)];
  }

  while (true) {
    // ---- even half: issue grp(n2)->Q, compute st n (buf0), stage n1 (P)->buf1
    issue_grp(Q, n2, n2 + CW2, ssA, E, ef4, f16v, src, eE, qE, eH, qH);
    __builtin_amdgcn_sched_barrier(0);
    compute_st(ms, buf0, n, E, g, m, lane, Bf);
    __builtin_amdgcn_sched_barrier(0);
    if (n1 >= nst) return;
    asm volatile("s_waitcnt vmcnt(6)" ::: "memory");
    __builtin_amdgcn_sched_barrier(0);
    stage_grp(buf1, P, n1, E, eE, qE, eH, qH);

    // ---- odd half: issue grp(n3)->P, compute st n1 (buf1), stage n2 (Q)->buf0
    issue_grp(P, n3, n3 + CW2, ssB, E, ef4, f16v, src, eE, qE, eH, qH);
    __builtin_amdgcn_sched_barrier(0);
    compute_st(ms, buf1, n1, E, g, m, lane, Bf);
    __builtin_amdgcn_sched_barrier(0);
    if (n2 >= nst) return;
    asm volatile("s_waitcnt vmcnt(6)" ::: "memory");
    __builtin_amdgcn_sched_barrier(0);
    stage_grp(buf0, Q, n2, E, eE, qE, eH, qH);

    n += CW2; n1 += CW2; n2 += CW2; n3 += CW2;
  }
}

// fragment-layout index of m[e][c]: (e>>4)*256 + ((e>>2)&3)*64 + c*4 + (e&3)
__device__ __forceinline__ float ms_at(const unsigned short* ms, int e, int c) {
  unsigned short u = ms[((e >> 4) << 8) + (((e >> 2) & 3) << 6) + (c << 2) + (e & 3)];
  return (float)__builtin_bit_cast(_Float16, u);
}

// Phase B: one 16-lane group per node; walk edge run, 4-edge (8B) vector loads.
__global__ __launch_bounds__(256) void segsum_kernel(
    const float* __restrict__ feat, const float* __restrict__ bias,
    const unsigned short* __restrict__ ms, const int* __restrict__ rp,
    float* __restrict__ out, int N) {
  int n = blockIdx.x * 16 + (threadIdx.x >> 4);
  int c = threadIdx.x & 15;
  if (n >= N) return;
  int lo = rp[n], hi = rp[n + 1];
  float sum = 0.f;
  int e = lo;
  while (e < hi && (e & 3)) { sum += ms_at(ms, e, c); ++e; }
  while (e + 4 <= hi) {
    const uint2 v = *reinterpret_cast<const uint2*>(
        ms + ((e >> 4) << 8) + (((e >> 2) & 3) << 6) + (c << 2));
    half2v x = __builtin_bit_cast(half2v, v.x);
    half2v y = __builtin_bit_cast(half2v, v.y);
    sum += (float)x[0] + (float)x[1] + (float)y[0] + (float)y[1];
    e += 4;
  }
  while (e < hi) { sum += ms_at(ms, e, c); ++e; }
  out[n * 16 + c] = sum + feat[n * 16 + c] + bias[c];
}

extern "C" void kernel_launch(void* const* d_in, const int* in_sizes, int n_in,
                              void* d_out, int out_size, void* d_ws, size_t ws_size,
                              hipStream_t stream) {
  const float* feat  = (const float*)d_in[0];
  const float* efeat = (const float*)d_in[1];
  const float* We    = (const float*)d_in[2];
  const float* be    = (const float*)d_in[3];
  const float* bias  = (const float*)d_in[4];
  const int*   src   = (const int*)d_in[5];
  const int*   dst   = (const int*)d_in[6];
  float* out = (float*)d_out;

  int E = in_sizes[5];
  int N = out_size / 16;

  unsigned short* wp  = (unsigned short*)d_ws;
  int* rp             = (int*)((char*)d_ws + RP_OFF);
  unsigned short* f16 = (unsigned short*)((char*)d_ws + F16_OFF);
  unsigned short* ms  = (unsigned short*)((char*)d_ws + MS_OFF);

  int sitems = WP_ELEMS;
  if (N + 1 > sitems) sitems = N + 1;
  if (N * 4 > sitems) sitems = N * 4;
  setup_kernel<<<(sitems + 255) / 256, 256, 0, stream>>>(We, be, feat, dst,
                                                         wp, rp, f16, E, N);

  int nst = (E + 31) / 32;
  int blocksA = min(NBLK, (nst + 3) / 4);
  edge_gemm_kernel<<<blocksA, 256, 0, stream>>>(efeat, src, wp, f16, ms, E);

  int blocksB = (N + 15) / 16;
  segsum_kernel<<<blocksB, 256, 0, stream>>>(feat, bias, ms, rp, out, N);
}